// Round 8
// baseline (170.919 us; speedup 1.0000x reference)
//
#include <hip/hip_runtime.h>

// Problem constants (fixed-shape problem)
#define BB 4
#define CC 16
#define KK 16
#define HWP (512 * 512)
#define TPB 512                   // pixels per block (4 waves x 128)
#define TPW 128                   // pixels per wave (4 MFMA groups of 32)
#define NTILES (HWP / TPB)        // 512 tiles per batch -> 2048 blocks
#define THREADS 256
#define NSLICE 32                 // atomic contention slices
#define WSTOT (64 + 1024 + 1024)  // floats per slice: cnt | sum | sq

typedef short bf16x8 __attribute__((ext_vector_type(8)));   // 8 bf16 (4 VGPRs)
typedef float f32x4 __attribute__((ext_vector_type(4)));    // MFMA C/D

__device__ __forceinline__ float fmaxf_(float a, float b) { return a > b ? a : b; }

// fp32 -> bf16 round-to-nearest-even (bit trick; no NaN in this data)
__device__ __forceinline__ unsigned short f2bf(float f) {
    unsigned u = __float_as_uint(f);
    u += 0x7FFFu + ((u >> 16) & 1u);
    return (unsigned short)(u >> 16);
}
__device__ __forceinline__ unsigned pkbf(float x, float y) {
    return (unsigned)f2bf(x) | ((unsigned)f2bf(y) << 16);
}
// two int mask vals -> packed bf16x2 {0,1}
__device__ __forceinline__ unsigned pkmask(int a, int b) {
    unsigned ua = (a > 0) ? 1u : 0u;
    unsigned ub = (b > 0) ? 1u : 0u;
    return (ua | (ub << 16)) * 0x3F80u;
}

// Latency-optimized MFMA kernel: no LDS, no barriers. Each lane loads its
// own mask plane + emb channel fragments directly (16B/lane coalesced),
// ALL 16 vector loads issued before any compute so they overlap in the
// vmcnt queue. 3 MFMAs per 32-px group (sum, sq, count via B=ones).
__global__ __launch_bounds__(THREADS) void disc_mfma_kernel(
    const float* __restrict__ emb, const int* __restrict__ masks,
    float* __restrict__ ws)   // NSLICE slices of [cnt 64 | sum 1024 | sq 1024]
{
    const int tid = threadIdx.x;
    const int lane = tid & 63;
    const int wave = tid >> 6;
    const int b = blockIdx.x / NTILES;
    const int tile = blockIdx.x % NTILES;
    const size_t base_px = (size_t)tile * TPB + wave * TPW;

    const int quad = lane >> 4;     // 0..3 -> k-range quad*8..+7 in each group
    const int r = lane & 15;        // A-row (mask idx) == B-col (channel idx)

    // lane (r,quad): mask plane r / emb channel r, pixels base+g*32+quad*8..+7
    const int*   mplane = masks + ((size_t)b * KK + r) * HWP + base_px + quad * 8;
    const float* eplane = emb   + ((size_t)b * CC + r) * HWP + base_px + quad * 8;

    // ---- issue all 16 loads up front (8 int4 + 8 float4, 16B/lane each) ----
    int4 m0[4], m1[4]; float4 e0[4], e1[4];
    #pragma unroll
    for (int g = 0; g < 4; ++g) {
        const int4* mp = (const int4*)(mplane + g * 32);
        m0[g] = mp[0]; m1[g] = mp[1];
        const float4* ep = (const float4*)(eplane + g * 32);
        e0[g] = ep[0]; e1[g] = ep[1];
    }

    union { bf16x8 v; unsigned short s[8]; } Bones;
    #pragma unroll
    for (int i = 0; i < 8; ++i) Bones.s[i] = 0x3F80;   // bf16 1.0

    f32x4 acc_s = {0.f, 0.f, 0.f, 0.f};
    f32x4 acc_q = {0.f, 0.f, 0.f, 0.f};
    f32x4 acc_c = {0.f, 0.f, 0.f, 0.f};

    #pragma unroll
    for (int g = 0; g < 4; ++g) {
        union { bf16x8 v; unsigned u[4]; } A;
        A.u[0] = pkmask(m0[g].x, m0[g].y);
        A.u[1] = pkmask(m0[g].z, m0[g].w);
        A.u[2] = pkmask(m1[g].x, m1[g].y);
        A.u[3] = pkmask(m1[g].z, m1[g].w);

        union { bf16x8 v; unsigned u[4]; } Bf, B2;
        Bf.u[0] = pkbf(e0[g].x, e0[g].y);
        Bf.u[1] = pkbf(e0[g].z, e0[g].w);
        Bf.u[2] = pkbf(e1[g].x, e1[g].y);
        Bf.u[3] = pkbf(e1[g].z, e1[g].w);
        B2.u[0] = pkbf(e0[g].x * e0[g].x, e0[g].y * e0[g].y);
        B2.u[1] = pkbf(e0[g].z * e0[g].z, e0[g].w * e0[g].w);
        B2.u[2] = pkbf(e1[g].x * e1[g].x, e1[g].y * e1[g].y);
        B2.u[3] = pkbf(e1[g].z * e1[g].z, e1[g].w * e1[g].w);

        acc_s = __builtin_amdgcn_mfma_f32_16x16x32_bf16(A.v, Bf.v, acc_s, 0, 0, 0);
        acc_q = __builtin_amdgcn_mfma_f32_16x16x32_bf16(A.v, B2.v, acc_q, 0, 0, 0);
        acc_c = __builtin_amdgcn_mfma_f32_16x16x32_bf16(A.v, Bones.v, acc_c, 0, 0, 0);
    }

    // ---- per-wave atomic epilogue (C/D: col=lane&15, row=(lane>>4)*4+reg) ----
    float* slice = ws + (size_t)((blockIdx.x * 4 + wave) & (NSLICE - 1)) * WSTOT;
    #pragma unroll
    for (int reg = 0; reg < 4; ++reg) {
        const int krow = quad * 4 + reg;
        atomicAdd(&slice[64 + ((size_t)b * KK + krow) * CC + r], acc_s[reg]);
        atomicAdd(&slice[64 + 1024 + ((size_t)b * KK + krow) * CC + r], acc_q[reg]);
    }
    if (r == 0) {   // count cols identical; col-0 lanes own rows quad*4..+3
        #pragma unroll
        for (int reg = 0; reg < 4; ++reg) {
            atomicAdd(&slice[b * KK + quad * 4 + reg], acc_c[reg]);
        }
    }
}

__global__ __launch_bounds__(256) void disc_finalize_kernel(
    const float* __restrict__ ws, float* __restrict__ out)
{
    __shared__ float red[WSTOT];             // slice-reduced [cnt|sum|sq]
    __shared__ float means[BB][KK][CC];
    __shared__ float partial[BB];
    const int tid = threadIdx.x;

    for (int idx = tid; idx < WSTOT; idx += 256) {
        float t = 0.f;
        #pragma unroll
        for (int s = 0; s < NSLICE; ++s) t += ws[(size_t)s * WSTOT + idx];
        red[idx] = t;
    }
    __syncthreads();

    const float* red_cnt = red;
    const float* red_sum = red + 64;
    const float* red_sq  = red + 64 + 1024;

    const int b = tid >> 6;       // one wave per batch
    const int lane = tid & 63;

    const float DELTA_PULL = 0.5f;
    const float DELTA_PUSH = 1.5f;
    const float EPS = 1e-6f;

    float cntk = 0.f;
    bool valid = false;
    float pull_k = 0.f;
    if (lane < KK) {
        int k = lane;
        cntk = red_cnt[b * KK + k];
        valid = cntk > 0.f;
        float safe = fmaxf_(cntk, 1.f);
        float acc_sq = 0.f, acc_ss = 0.f;
        #pragma unroll
        for (int c = 0; c < CC; ++c) {
            float sv = red_sum[(b * KK + k) * CC + c];
            means[b][k][c] = sv / safe;
            acc_sq += red_sq[(b * KK + k) * CC + c];
            acc_ss += sv * sv;
        }
        if (valid) pull_k = (acc_sq - acc_ss / cntk) / (cntk + EPS);
    }

    unsigned long long bal = __ballot(lane < KK && valid);
    float M = (float)__popcll(bal);

    float ps = pull_k;
    #pragma unroll
    for (int d = 32; d >= 1; d >>= 1) ps += __shfl_xor(ps, d, 64);
    float pull_b = ps / fmaxf_(M, 1.f);

    __syncthreads();

    float push = 0.f;
    for (int t = lane; t < KK * KK; t += 64) {
        int i = t >> 4, j = t & 15;
        if (i < j && ((bal >> i) & 1ull) && ((bal >> j) & 1ull)) {
            float d2 = 1e-12f;
            #pragma unroll
            for (int c = 0; c < CC; ++c) {
                float df = means[b][i][c] - means[b][j][c];
                d2 = fmaf(df, df, d2);
            }
            float dist = sqrtf(d2);
            float h = fmaxf_(DELTA_PUSH - dist, 0.f);
            push += h * h;
        }
    }
    #pragma unroll
    for (int d = 32; d >= 1; d >>= 1) push += __shfl_xor(push, d, 64);

    if (lane == 0) {
        float npairs = M * (M - 1.f) * 0.5f;
        float push_b = (M > 1.f) ? push / fmaxf_(npairs, 1.f) : 0.f;
        partial[b] = DELTA_PULL * pull_b + push_b;
    }
    __syncthreads();
    if (tid == 0) {
        out[0] = (partial[0] + partial[1] + partial[2] + partial[3]) * 0.25f;
    }
}

extern "C" void kernel_launch(void* const* d_in, const int* in_sizes, int n_in,
                              void* d_out, int out_size, void* d_ws, size_t ws_size,
                              hipStream_t stream) {
    const float* emb = (const float*)d_in[0];
    const int* masks = (const int*)d_in[1];
    float* ws = (float*)d_ws;

    hipMemsetAsync(d_ws, 0, NSLICE * WSTOT * sizeof(float), stream);

    dim3 grid(BB * NTILES);
    disc_mfma_kernel<<<grid, THREADS, 0, stream>>>(emb, masks, ws);
    disc_finalize_kernel<<<1, 256, 0, stream>>>(ws, (float*)d_out);
}

// Round 9
// 158.737 us; speedup vs baseline: 1.0767x; 1.0767x over previous
//
#include <hip/hip_runtime.h>

// Problem constants (fixed-shape problem)
#define BB 4
#define CC 16
#define KK 16
#define HWP (512 * 512)
#define TPB 1024                  // pixels per block (4 waves x 256)
#define TPW 256                   // pixels per wave (8 MFMA groups of 32)
#define NTILES (HWP / TPB)        // 256 tiles per batch -> 1024 blocks
#define THREADS 256
#define NGROUP (TPW / 32)         // 8
#define NSLICE 16                 // atomic contention slices
#define WSTOT (64 + 1024 + 1024)  // floats per slice: cnt | sum | sq

typedef short bf16x8 __attribute__((ext_vector_type(8)));   // 8 bf16 (4 VGPRs)
typedef float f32x4 __attribute__((ext_vector_type(4)));    // MFMA C/D

__device__ __forceinline__ float fmaxf_(float a, float b) { return a > b ? a : b; }

// fp32 -> bf16 round-to-nearest-even (bit trick; no NaN in this data)
__device__ __forceinline__ unsigned short f2bf(float f) {
    unsigned u = __float_as_uint(f);
    u += 0x7FFFu + ((u >> 16) & 1u);
    return (unsigned short)(u >> 16);
}
__device__ __forceinline__ unsigned pkbf(float x, float y) {
    return (unsigned)f2bf(x) | ((unsigned)f2bf(y) << 16);
}
// two int mask vals -> packed bf16x2 {0,1}
__device__ __forceinline__ unsigned pkmask(int a, int b) {
    unsigned ua = (a > 0) ? 1u : 0u;
    unsigned ub = (b > 0) ? 1u : 0u;
    return (ua | (ub << 16)) * 0x3F80u;
}

// MFMA kernel, latency-tuned: direct global loads (no mask-pack LDS),
// one-group-ahead prefetch pinned with sched_barrier(0) so the compiler
// can't sink the loads (round-8 lesson: it will, leaving VGPR=28 and no
// MLP). Block-level padded-LDS reduction cuts global atomics 4x
// (round 7->8 measured ~5.4us per million device-scope atomics).
__global__ __launch_bounds__(THREADS) void disc_mfma_kernel(
    const float* __restrict__ emb, const int* __restrict__ masks,
    float* __restrict__ ws)   // NSLICE slices of [cnt 64 | sum 1024 | sq 1024]
{
    __shared__ float redbuf[4][64][9];   // pad 8->9: stride-9 banks, conflict-free
    __shared__ float cnt_red[4][16];

    const int tid = threadIdx.x;
    const int lane = tid & 63;
    const int wave = tid >> 6;
    const int b = blockIdx.x / NTILES;
    const int tile = blockIdx.x % NTILES;
    const size_t base_px = (size_t)tile * TPB + wave * TPW;

    const int quad = lane >> 4;     // 0..3 -> pixel sub-offset quad*8
    const int r = lane & 15;        // A-row (mask idx) == B-col (channel idx)

    // lane (r,quad): mask plane r / emb channel r, pixels base+g*32+quad*8..+7
    const int*   mp = masks + ((size_t)b * KK + r) * HWP + base_px + quad * 8;
    const float* ep = emb   + ((size_t)b * CC + r) * HWP + base_px + quad * 8;

    union { bf16x8 v; unsigned short s[8]; } Bones;
    #pragma unroll
    for (int i = 0; i < 8; ++i) Bones.s[i] = 0x3F80;   // bf16 1.0

    f32x4 acc_s = {0.f, 0.f, 0.f, 0.f};
    f32x4 acc_q = {0.f, 0.f, 0.f, 0.f};
    f32x4 acc_c = {0.f, 0.f, 0.f, 0.f};

    // prologue: load group 0
    int4 m0c = ((const int4*)mp)[0], m1c = ((const int4*)mp)[1];
    float4 e0c = ((const float4*)ep)[0], e1c = ((const float4*)ep)[1];

    #pragma unroll
    for (int g = 0; g < NGROUP; ++g) {
        int4 m0n, m1n; float4 e0n, e1n;
        if (g + 1 < NGROUP) {
            const int*   mpn = mp + (g + 1) * 32;
            const float* epn = ep + (g + 1) * 32;
            m0n = ((const int4*)mpn)[0]; m1n = ((const int4*)mpn)[1];
            e0n = ((const float4*)epn)[0]; e1n = ((const float4*)epn)[1];
        }
#if __has_builtin(__builtin_amdgcn_sched_barrier)
        __builtin_amdgcn_sched_barrier(0);   // pin prefetch above the compute
#endif
        union { bf16x8 v; unsigned u[4]; } A;
        A.u[0] = pkmask(m0c.x, m0c.y);
        A.u[1] = pkmask(m0c.z, m0c.w);
        A.u[2] = pkmask(m1c.x, m1c.y);
        A.u[3] = pkmask(m1c.z, m1c.w);

        union { bf16x8 v; unsigned u[4]; } Bf, B2;
        Bf.u[0] = pkbf(e0c.x, e0c.y);
        Bf.u[1] = pkbf(e0c.z, e0c.w);
        Bf.u[2] = pkbf(e1c.x, e1c.y);
        Bf.u[3] = pkbf(e1c.z, e1c.w);
        B2.u[0] = pkbf(e0c.x * e0c.x, e0c.y * e0c.y);
        B2.u[1] = pkbf(e0c.z * e0c.z, e0c.w * e0c.w);
        B2.u[2] = pkbf(e1c.x * e1c.x, e1c.y * e1c.y);
        B2.u[3] = pkbf(e1c.z * e1c.z, e1c.w * e1c.w);

        acc_s = __builtin_amdgcn_mfma_f32_16x16x32_bf16(A.v, Bf.v, acc_s, 0, 0, 0);
        acc_q = __builtin_amdgcn_mfma_f32_16x16x32_bf16(A.v, B2.v, acc_q, 0, 0, 0);
        acc_c = __builtin_amdgcn_mfma_f32_16x16x32_bf16(A.v, Bones.v, acc_c, 0, 0, 0);

        if (g + 1 < NGROUP) { m0c = m0n; m1c = m1n; e0c = e0n; e1c = e1n; }
    }

    // ---- block-level reduction in padded LDS (C/D: col=lane&15, row=quad*4+reg) ----
    #pragma unroll
    for (int j = 0; j < 4; ++j) {
        redbuf[wave][lane][j] = acc_s[j];
        redbuf[wave][lane][4 + j] = acc_q[j];
    }
    if (r == 0) {   // count cols identical; col-0 lanes own rows quad*4..+3
        #pragma unroll
        for (int reg = 0; reg < 4; ++reg) cnt_red[wave][quad * 4 + reg] = acc_c[reg];
    }
    __syncthreads();

    float* slice = ws + (size_t)(blockIdx.x & (NSLICE - 1)) * WSTOT;
    #pragma unroll
    for (int t = 0; t < 2; ++t) {
        const int fi = tid + t * THREADS;          // 0..511
        const int l2 = fi >> 3, j = fi & 7;
        float v = redbuf[0][l2][j] + redbuf[1][l2][j]
                + redbuf[2][l2][j] + redbuf[3][l2][j];
        const int reg = j & 3, isq = j >> 2;
        const int krow = (l2 >> 4) * 4 + reg;
        const int ccol = l2 & 15;
        atomicAdd(&slice[64 + isq * 1024 + ((size_t)b * KK + krow) * CC + ccol], v);
    }
    if (tid < KK) {
        float ctot = cnt_red[0][tid] + cnt_red[1][tid] + cnt_red[2][tid] + cnt_red[3][tid];
        atomicAdd(&slice[b * KK + tid], ctot);
    }
}

__global__ __launch_bounds__(256) void disc_finalize_kernel(
    const float* __restrict__ ws, float* __restrict__ out)
{
    __shared__ float red[WSTOT];             // slice-reduced [cnt|sum|sq]
    __shared__ float means[BB][KK][CC];
    __shared__ float partial[BB];
    const int tid = threadIdx.x;

    for (int idx = tid; idx < WSTOT; idx += 256) {
        float t = 0.f;
        #pragma unroll
        for (int s = 0; s < NSLICE; ++s) t += ws[(size_t)s * WSTOT + idx];
        red[idx] = t;
    }
    __syncthreads();

    const float* red_cnt = red;
    const float* red_sum = red + 64;
    const float* red_sq  = red + 64 + 1024;

    const int b = tid >> 6;       // one wave per batch
    const int lane = tid & 63;

    const float DELTA_PULL = 0.5f;
    const float DELTA_PUSH = 1.5f;
    const float EPS = 1e-6f;

    float cntk = 0.f;
    bool valid = false;
    float pull_k = 0.f;
    if (lane < KK) {
        int k = lane;
        cntk = red_cnt[b * KK + k];
        valid = cntk > 0.f;
        float safe = fmaxf_(cntk, 1.f);
        float acc_sq = 0.f, acc_ss = 0.f;
        #pragma unroll
        for (int c = 0; c < CC; ++c) {
            float sv = red_sum[(b * KK + k) * CC + c];
            means[b][k][c] = sv / safe;
            acc_sq += red_sq[(b * KK + k) * CC + c];
            acc_ss += sv * sv;
        }
        if (valid) pull_k = (acc_sq - acc_ss / cntk) / (cntk + EPS);
    }

    unsigned long long bal = __ballot(lane < KK && valid);
    float M = (float)__popcll(bal);

    float ps = pull_k;
    #pragma unroll
    for (int d = 32; d >= 1; d >>= 1) ps += __shfl_xor(ps, d, 64);
    float pull_b = ps / fmaxf_(M, 1.f);

    __syncthreads();

    float push = 0.f;
    for (int t = lane; t < KK * KK; t += 64) {
        int i = t >> 4, j = t & 15;
        if (i < j && ((bal >> i) & 1ull) && ((bal >> j) & 1ull)) {
            float d2 = 1e-12f;
            #pragma unroll
            for (int c = 0; c < CC; ++c) {
                float df = means[b][i][c] - means[b][j][c];
                d2 = fmaf(df, df, d2);
            }
            float dist = sqrtf(d2);
            float h = fmaxf_(DELTA_PUSH - dist, 0.f);
            push += h * h;
        }
    }
    #pragma unroll
    for (int d = 32; d >= 1; d >>= 1) push += __shfl_xor(push, d, 64);

    if (lane == 0) {
        float npairs = M * (M - 1.f) * 0.5f;
        float push_b = (M > 1.f) ? push / fmaxf_(npairs, 1.f) : 0.f;
        partial[b] = DELTA_PULL * pull_b + push_b;
    }
    __syncthreads();
    if (tid == 0) {
        out[0] = (partial[0] + partial[1] + partial[2] + partial[3]) * 0.25f;
    }
}

extern "C" void kernel_launch(void* const* d_in, const int* in_sizes, int n_in,
                              void* d_out, int out_size, void* d_ws, size_t ws_size,
                              hipStream_t stream) {
    const float* emb = (const float*)d_in[0];
    const int* masks = (const int*)d_in[1];
    float* ws = (float*)d_ws;

    hipMemsetAsync(d_ws, 0, NSLICE * WSTOT * sizeof(float), stream);

    dim3 grid(BB * NTILES);
    disc_mfma_kernel<<<grid, THREADS, 0, stream>>>(emb, masks, ws);
    disc_finalize_kernel<<<1, 256, 0, stream>>>(ws, (float*)d_out);
}

// Round 10
// 155.415 us; speedup vs baseline: 1.0998x; 1.0214x over previous
//
#include <hip/hip_runtime.h>

// Problem constants (fixed-shape problem)
#define BB 4
#define CC 16
#define KK 16
#define HWP (512 * 512)
#define TPB 1024                  // pixels per block (4 waves x 256)
#define TPW 256                   // pixels per wave (8 MFMA groups of 32)
#define NTILES (HWP / TPB)        // 256 tiles per batch -> 1024 blocks
#define THREADS 256
#define NGROUP (TPW / 32)         // 8
#define NSLICE 16                 // atomic contention slices
#define WSTOT (64 + 1024 + 1024)  // floats per slice: cnt | sum | sq

typedef short bf16x8 __attribute__((ext_vector_type(8)));   // 8 bf16 (4 VGPRs)
typedef float f32x4 __attribute__((ext_vector_type(4)));    // MFMA C/D

__device__ __forceinline__ float fmaxf_(float a, float b) { return a > b ? a : b; }

// fp32 -> bf16 round-to-nearest-even (bit trick; no NaN in this data)
__device__ __forceinline__ unsigned short f2bf(float f) {
    unsigned u = __float_as_uint(f);
    u += 0x7FFFu + ((u >> 16) & 1u);
    return (unsigned short)(u >> 16);
}
__device__ __forceinline__ unsigned pkbf(float x, float y) {
    return (unsigned)f2bf(x) | ((unsigned)f2bf(y) << 16);
}

// Best-known composition (rounds 6-9 evidence):
//  - per-wave LDS mask pack with int4 loads (16 instrs/wave, round-7 base)
//  - no barriers in the hot path (wave reads only its own LDS region)
//  - 3 MFMAs per 32-px group (sum, sq, count via B=ones)
//  - block-level padded-LDS reduce -> 528 atomics/block (round-9, -5.4us/M)
//  - NO sched_barrier / manual prefetch (compiler defeats it; rounds 8-9)
__global__ __launch_bounds__(THREADS) void disc_mfma_kernel(
    const float* __restrict__ emb, const int* __restrict__ masks,
    float* __restrict__ ws)   // NSLICE slices of [cnt 64 | sum 1024 | sq 1024]
{
    __shared__ __align__(16) unsigned short bits[TPB];  // 2 KB, per-wave regions
    __shared__ float redbuf[4][64][9];   // pad 8->9: conflict-light reduce
    __shared__ float cnt_red[4][16];

    const int tid = threadIdx.x;
    const int lane = tid & 63;
    const int wave = tid >> 6;
    const int b = blockIdx.x / NTILES;
    const int tile = blockIdx.x % NTILES;
    const size_t base_px = (size_t)tile * TPB + wave * TPW;

    const int quad = lane >> 4;     // 0..3
    const int r = lane & 15;        // A-row (mask idx) == B-col (channel idx)

    // ---- phase 1: pack this wave's 256 px of mask bits (int4: 4 px/lane) ----
    const int* mbase = masks + (size_t)b * KK * HWP + base_px + 4 * lane;
    unsigned v0 = 0, v1 = 0, v2 = 0, v3 = 0;
    #pragma unroll
    for (int k = 0; k < KK; ++k) {
        int4 mm = *(const int4*)(mbase + (size_t)k * HWP);
        v0 |= (mm.x > 0 ? 1u : 0u) << k;
        v1 |= (mm.y > 0 ? 1u : 0u) << k;
        v2 |= (mm.z > 0 ? 1u : 0u) << k;
        v3 |= (mm.w > 0 ? 1u : 0u) << k;
    }
    uint2 pk;
    pk.x = v0 | (v1 << 16);
    pk.y = v2 | (v3 << 16);
    ((uint2*)bits)[(wave * TPW) / 4 + lane] = pk;   // pixels base+4*lane..+3
    // no barrier: this wave reads only bits[wave*TPW .. +255], written above
    // by its own lanes (DS ops wave-ordered; compiler emits the lgkmcnt wait)

    // ---- phase 2: 8 groups of 32 px; 3 MFMAs each ----
    union { bf16x8 v; unsigned short s[8]; } Bones;
    #pragma unroll
    for (int i = 0; i < 8; ++i) Bones.s[i] = 0x3F80;   // bf16 1.0

    const float* ebase = emb + ((size_t)b * CC + r) * HWP + base_px;  // channel r

    f32x4 acc_s = {0.f, 0.f, 0.f, 0.f};
    f32x4 acc_q = {0.f, 0.f, 0.f, 0.f};
    f32x4 acc_c = {0.f, 0.f, 0.f, 0.f};

    #pragma unroll
    for (int g = 0; g < NGROUP; ++g) {
        const int p0 = wave * TPW + g * 32;

        // A-frag: mask bit r of pixels p0+quad*8..+7 (16B LDS read, 4-lane bcast)
        uint4 bw = *(const uint4*)&bits[p0 + quad * 8];
        union { bf16x8 v; unsigned u[4]; } A;
        A.u[0] = ((bw.x >> r) & 0x00010001u) * 0x3F80u;
        A.u[1] = ((bw.y >> r) & 0x00010001u) * 0x3F80u;
        A.u[2] = ((bw.z >> r) & 0x00010001u) * 0x3F80u;
        A.u[3] = ((bw.w >> r) & 0x00010001u) * 0x3F80u;

        // B-frags: channel r, pixels g*32+quad*8..+7 (two float4 loads)
        const float4* ep = (const float4*)(ebase + g * 32 + quad * 8);
        float4 f0 = ep[0], f1 = ep[1];
        union { bf16x8 v; unsigned u[4]; } Bf, B2;
        Bf.u[0] = pkbf(f0.x, f0.y);
        Bf.u[1] = pkbf(f0.z, f0.w);
        Bf.u[2] = pkbf(f1.x, f1.y);
        Bf.u[3] = pkbf(f1.z, f1.w);
        B2.u[0] = pkbf(f0.x * f0.x, f0.y * f0.y);
        B2.u[1] = pkbf(f0.z * f0.z, f0.w * f0.w);
        B2.u[2] = pkbf(f1.x * f1.x, f1.y * f1.y);
        B2.u[3] = pkbf(f1.z * f1.z, f1.w * f1.w);

        acc_s = __builtin_amdgcn_mfma_f32_16x16x32_bf16(A.v, Bf.v, acc_s, 0, 0, 0);
        acc_q = __builtin_amdgcn_mfma_f32_16x16x32_bf16(A.v, B2.v, acc_q, 0, 0, 0);
        acc_c = __builtin_amdgcn_mfma_f32_16x16x32_bf16(A.v, Bones.v, acc_c, 0, 0, 0);
    }

    // ---- block-level reduction (C/D: col=lane&15, row=quad*4+reg) ----
    #pragma unroll
    for (int j = 0; j < 4; ++j) {
        redbuf[wave][lane][j] = acc_s[j];
        redbuf[wave][lane][4 + j] = acc_q[j];
    }
    if (r == 0) {   // count cols identical; col-0 lanes own rows quad*4..+3
        #pragma unroll
        for (int reg = 0; reg < 4; ++reg) cnt_red[wave][quad * 4 + reg] = acc_c[reg];
    }
    __syncthreads();

    float* slice = ws + (size_t)(blockIdx.x & (NSLICE - 1)) * WSTOT;
    #pragma unroll
    for (int t = 0; t < 2; ++t) {
        const int fi = tid + t * THREADS;          // 0..511
        const int l2 = fi >> 3, j = fi & 7;
        float v = redbuf[0][l2][j] + redbuf[1][l2][j]
                + redbuf[2][l2][j] + redbuf[3][l2][j];
        const int reg = j & 3, isq = j >> 2;
        const int krow = (l2 >> 4) * 4 + reg;
        const int ccol = l2 & 15;
        atomicAdd(&slice[64 + isq * 1024 + ((size_t)b * KK + krow) * CC + ccol], v);
    }
    if (tid < KK) {
        float ctot = cnt_red[0][tid] + cnt_red[1][tid] + cnt_red[2][tid] + cnt_red[3][tid];
        atomicAdd(&slice[b * KK + tid], ctot);
    }
}

__global__ __launch_bounds__(256) void disc_finalize_kernel(
    const float* __restrict__ ws, float* __restrict__ out)
{
    __shared__ float red[WSTOT];             // slice-reduced [cnt|sum|sq]
    __shared__ float means[BB][KK][CC];
    __shared__ float partial[BB];
    const int tid = threadIdx.x;

    for (int idx = tid; idx < WSTOT; idx += 256) {
        float t = 0.f;
        #pragma unroll
        for (int s = 0; s < NSLICE; ++s) t += ws[(size_t)s * WSTOT + idx];
        red[idx] = t;
    }
    __syncthreads();

    const float* red_cnt = red;
    const float* red_sum = red + 64;
    const float* red_sq  = red + 64 + 1024;

    const int b = tid >> 6;       // one wave per batch
    const int lane = tid & 63;

    const float DELTA_PULL = 0.5f;
    const float DELTA_PUSH = 1.5f;
    const float EPS = 1e-6f;

    float cntk = 0.f;
    bool valid = false;
    float pull_k = 0.f;
    if (lane < KK) {
        int k = lane;
        cntk = red_cnt[b * KK + k];
        valid = cntk > 0.f;
        float safe = fmaxf_(cntk, 1.f);
        float acc_sq = 0.f, acc_ss = 0.f;
        #pragma unroll
        for (int c = 0; c < CC; ++c) {
            float sv = red_sum[(b * KK + k) * CC + c];
            means[b][k][c] = sv / safe;
            acc_sq += red_sq[(b * KK + k) * CC + c];
            acc_ss += sv * sv;
        }
        if (valid) pull_k = (acc_sq - acc_ss / cntk) / (cntk + EPS);
    }

    unsigned long long bal = __ballot(lane < KK && valid);
    float M = (float)__popcll(bal);

    float ps = pull_k;
    #pragma unroll
    for (int d = 32; d >= 1; d >>= 1) ps += __shfl_xor(ps, d, 64);
    float pull_b = ps / fmaxf_(M, 1.f);

    __syncthreads();

    float push = 0.f;
    for (int t = lane; t < KK * KK; t += 64) {
        int i = t >> 4, j = t & 15;
        if (i < j && ((bal >> i) & 1ull) && ((bal >> j) & 1ull)) {
            float d2 = 1e-12f;
            #pragma unroll
            for (int c = 0; c < CC; ++c) {
                float df = means[b][i][c] - means[b][j][c];
                d2 = fmaf(df, df, d2);
            }
            float dist = sqrtf(d2);
            float h = fmaxf_(DELTA_PUSH - dist, 0.f);
            push += h * h;
        }
    }
    #pragma unroll
    for (int d = 32; d >= 1; d >>= 1) push += __shfl_xor(push, d, 64);

    if (lane == 0) {
        float npairs = M * (M - 1.f) * 0.5f;
        float push_b = (M > 1.f) ? push / fmaxf_(npairs, 1.f) : 0.f;
        partial[b] = DELTA_PULL * pull_b + push_b;
    }
    __syncthreads();
    if (tid == 0) {
        out[0] = (partial[0] + partial[1] + partial[2] + partial[3]) * 0.25f;
    }
}

extern "C" void kernel_launch(void* const* d_in, const int* in_sizes, int n_in,
                              void* d_out, int out_size, void* d_ws, size_t ws_size,
                              hipStream_t stream) {
    const float* emb = (const float*)d_in[0];
    const int* masks = (const int*)d_in[1];
    float* ws = (float*)d_ws;

    hipMemsetAsync(d_ws, 0, NSLICE * WSTOT * sizeof(float), stream);

    dim3 grid(BB * NTILES);
    disc_mfma_kernel<<<grid, THREADS, 0, stream>>>(emb, masks, ws);
    disc_finalize_kernel<<<1, 256, 0, stream>>>(ws, (float*)d_out);
}